// Round 16
// baseline (111.524 us; speedup 1.0000x reference)
//
#include <hip/hip_runtime.h>
#include <hip/hip_bf16.h>

// DeepKernelAttention: linear attention with MLP feature maps.
// R16: R15's CU-resident weights x 2x concurrency via 16-row units (R13's
// verified body). stage1: 8-wave blocks, per-wave work LDS 6.25KB (LDT=16),
// block = 96KB sW + 50KB = 146KB -> 1 block/CU = 8 waves/CU (R15: 4).
// stage2: 8-wave blocks, 66KB -> 2 blocks/CU = 16 waves/CU (R15: 8).

typedef __attribute__((ext_vector_type(8))) short short8;
typedef __attribute__((ext_vector_type(4))) float f32x4;
typedef unsigned int u32;
typedef unsigned short u16;

#define MFMA(A,B,C) __builtin_amdgcn_mfma_f32_16x16x32_bf16((A),(B),(C),0,0,0)
#define SBAR() __builtin_amdgcn_sched_barrier(0)

#define LDH 136   // H1 leading dim; 272B row, 16B aligned
#define LDT 16    // KT/VT leading dim (16 rows); 32B row, 16B aligned
#define INVS 0.3535533905932738f   // 64^-0.25

__device__ __forceinline__ u16 bfc(float x){
  __hip_bfloat16 h = __float2bfloat16(x);
  return __bfloat16_as_ushort(h);
}
__device__ __forceinline__ u32 pack2(float a, float b){
  return (u32)bfc(a) | ((u32)bfc(b) << 16);
}
__device__ __forceinline__ float b2f(u16 w){
  return __uint_as_float(((u32)w) << 16);
}
__device__ __forceinline__ short8 cvt8(f32x4 lo, f32x4 hi){
  short8 r;
  r[0]=(short)bfc(lo[0]); r[1]=(short)bfc(lo[1]);
  r[2]=(short)bfc(lo[2]); r[3]=(short)bfc(lo[3]);
  r[4]=(short)bfc(hi[0]); r[5]=(short)bfc(hi[1]);
  r[6]=(short)bfc(hi[2]); r[7]=(short)bfc(hi[3]);
  return r;
}
// tanh-approx gelu
__device__ __forceinline__ float gelu_f(float x){
  float s = x*x;
  float u = x * __builtin_fmaf(s, 0.035677408136300125f, 0.7978845608028654f);
  float e = __builtin_amdgcn_exp2f(u * -2.885390081777927f);
  return x * __builtin_amdgcn_rcpf(1.0f + e);
}
// direct global->LDS DMA: uniform LDS base, HW adds lane*16B
__device__ __forceinline__ void gld_lds16(const u16* gsrc, u16* ldst){
  __builtin_amdgcn_global_load_lds(
      (const __attribute__((address_space(1))) void*)gsrc,
      (__attribute__((address_space(3))) void*)ldst, 16, 0, 0);
}

// ---- weight prep: fragment-linear bf16 layout (R4/R10 ordering) ----
// chunks 0-31 Wq1 (mt*4+ks4) | 32-63 Wq2*INVS (n2*4+ks4) | 64-79 Wv1
// (mt*2+ks2) | 80-95 Wv2 (n2*4+ks4). chunk c, lane l, elem e at wt[(c*64+l)*8+e].
__global__ void dk_prep(const float* __restrict__ Wq1, const float* __restrict__ Wq2,
                        const float* __restrict__ Wv1, const float* __restrict__ Wv2,
                        u16* __restrict__ wt){
  int i = blockIdx.x*256 + threadIdx.x;   // grid 192*256 = 49152 exact
  int e = i & 7;
  int lane = (i >> 3) & 63;
  int chunk = i >> 9;
  int c = lane & 15, g = lane >> 4;
  int k0 = 8*g + e;
  float v;
  if (chunk < 32){
    int mt = chunk >> 2, ks4 = chunk & 3;
    v = Wq1[(ks4*32 + k0)*128 + mt*16 + c];
  } else if (chunk < 64){
    int ch = chunk - 32; int mt = ch >> 2, ks4 = ch & 3;
    v = Wq2[(ks4*32 + k0)*128 + mt*16 + c] * INVS;
  } else if (chunk < 80){
    int ch = chunk - 64; int mt = ch >> 1, ks2 = ch & 1;
    v = Wv1[(ks2*32 + k0)*128 + mt*16 + c];
  } else {
    int ch = chunk - 80; int n2 = ch >> 2, ks4 = ch & 3;
    v = Wv2[(ks4*32 + k0)*64 + n2*16 + c];
  }
  wt[i] = bfc(v);
}

// ---- stage 1: persistent 8-wave blocks; 96KB weights in LDS; 16-row units ----
__global__ __launch_bounds__(512, 2) void dk_stage1(
    const float* __restrict__ ksp, const float* __restrict__ kssp,
    const float* __restrict__ vsp, const int* __restrict__ vlen,
    const float* __restrict__ bq1, const float* __restrict__ bq2,
    const float* __restrict__ bv1, const float* __restrict__ bv2,
    const u16* __restrict__ wt, float* __restrict__ kvgr, int repmask)
{
  __shared__ u16 sA[8][2176];   // per-wave: H1 (2176 u16) / KT (2048 u16) overlay
  __shared__ u16 sB[8][1024];   // per-wave: VT (1024 u16)
  __shared__ u16 sW[49152];     // 96KB: all weights, chunk ch at sW+ch*512
  const int tid = threadIdx.x;
  const int w = tid >> 6, l = tid & 63;
  const int c = l & 15, g = l >> 4;

  // stage all 96 weight chunks once (12 DMA per wave, zero VGPR)
  #pragma unroll
  for (int j=0; j<12; ++j){
    const int ch = w*12 + j;
    gld_lds16(wt + ((size_t)ch*64 + l)*8, &sW[(size_t)ch*512]);
  }

  // lane-parallel inclusive prefix of 16-row unit counts over 16 batches
  int pfx = (l < 16) ? ((vlen[l] + 15) >> 4) : 0;
  #pragma unroll
  for (int m=1; m<16; m<<=1){
    int v = __shfl_up(pfx, m, 64);
    if (l >= m) pfx += v;
  }
  const int T = __shfl(pfx, 15, 64);
  __syncthreads();                     // weights resident

  u16* H1 = sA[w];
  u16* KT = sA[w];                     // overlay (H1 dead after GEMM2 reads)
  u16* VT = sB[w];
  const f32x4 z4 = {0.f,0.f,0.f,0.f};
  const short8 zf = {0,0,0,0,0,0,0,0};

  for (int u = blockIdx.x*8 + w; u < T; u += gridDim.x*8){
    unsigned long long mk = __ballot(l < 16 && pfx <= u);
    const int b = __popcll(mk);
    const int ju = u - (b ? __shfl(pfx, b-1, 64) : 0);
    const int len = vlen[b];
    const int rbase = ju*16;
    const int rep = u & repmask;
    const size_t row0 = (size_t)b*8192 + rbase;

    // ---- v chain: T-GEMM1v (K=64), 4 x-loads pinned ----
    {
      f32x4 xvf[4];
      #pragma unroll
      for (int ks2=0; ks2<2; ++ks2){
        const float* src = vsp + (row0 + c)*64 + ks2*32 + 8*g;
        xvf[ks2*2+0] = *(const f32x4*)src;
        xvf[ks2*2+1] = *(const f32x4*)(src+4);
      }
      SBAR();
      short8 xv[2];
      #pragma unroll
      for (int ks2=0; ks2<2; ++ks2)
        xv[ks2] = cvt8(xvf[ks2*2+0], xvf[ks2*2+1]);
      f32x4 av[8];
      #pragma unroll
      for (int mt=0; mt<8; ++mt) av[mt] = z4;
      #pragma unroll
      for (int ks2=0; ks2<2; ++ks2){
        short8 wa[8];
        #pragma unroll
        for (int mt=0; mt<8; ++mt)
          wa[mt] = *(const short8*)&sW[(size_t)(64 + mt*2+ks2)*512 + l*8];
        SBAR();
        #pragma unroll
        for (int mt=0; mt<8; ++mt)
          av[mt] = MFMA(wa[mt], xv[ks2], av[mt]);
      }
      #pragma unroll
      for (int mt=0; mt<8; ++mt){
        const f32x4 bia = *(const f32x4*)&bv1[mt*16 + 4*g];
        uint2 pp;
        pp.x = pack2(gelu_f(av[mt][0]+bia[0]), gelu_f(av[mt][1]+bia[1]));
        pp.y = pack2(gelu_f(av[mt][2]+bia[2]), gelu_f(av[mt][3]+bia[3]));
        *(uint2*)&H1[c*LDH + mt*16 + 4*g] = pp;
      }
    }
    // ---- N-GEMM2v: N=64 -> VT[vdim][row] ----
    {
      f32x4 acv[4];
      #pragma unroll
      for (int n2=0; n2<4; ++n2) acv[n2] = z4;
      #pragma unroll
      for (int ks4=0; ks4<4; ++ks4){
        short8 wb[4];
        #pragma unroll
        for (int n2=0; n2<4; ++n2)
          wb[n2] = *(const short8*)&sW[(size_t)(80 + n2*4+ks4)*512 + l*8];
        SBAR();
        const short8 ah = *(const short8*)&H1[c*LDH + ks4*32 + 8*g];
        #pragma unroll
        for (int n2=0; n2<4; ++n2)
          acv[n2] = MFMA(ah, wb[n2], acv[n2]);
      }
      #pragma unroll
      for (int n2=0; n2<4; ++n2){
        const float bb = bv2[n2*16 + c];
        uint2 pp;
        pp.x = pack2(acv[n2][0]+bb, acv[n2][1]+bb);
        pp.y = pack2(acv[n2][2]+bb, acv[n2][3]+bb);
        *(uint2*)&VT[(n2*16+c)*LDT + 4*g] = pp;
      }
    }
    // ---- k chain: T-GEMM1k, 8 x-loads pinned ----
    {
      f32x4 xkf[8];
      #pragma unroll
      for (int ks4=0; ks4<4; ++ks4){
        const int kk = ks4*32 + 8*g;
        const float* src = (ks4 < 2) ? (kssp + (row0 + c)*64 + kk)
                                     : (ksp  + (row0 + c)*64 + (kk - 64));
        xkf[ks4*2+0] = *(const f32x4*)src;
        xkf[ks4*2+1] = *(const f32x4*)(src+4);
      }
      SBAR();
      short8 xk[4];
      #pragma unroll
      for (int ks4=0; ks4<4; ++ks4)
        xk[ks4] = cvt8(xkf[ks4*2+0], xkf[ks4*2+1]);
      f32x4 acc[8];
      #pragma unroll
      for (int mt=0; mt<8; ++mt) acc[mt] = z4;
      #pragma unroll
      for (int ks4=0; ks4<4; ++ks4){
        short8 wa[8];
        #pragma unroll
        for (int mt=0; mt<8; ++mt)
          wa[mt] = *(const short8*)&sW[(size_t)(mt*4+ks4)*512 + l*8];
        SBAR();
        #pragma unroll
        for (int mt=0; mt<8; ++mt)
          acc[mt] = MFMA(wa[mt], xk[ks4], acc[mt]);
      }
      #pragma unroll
      for (int mt=0; mt<8; ++mt){
        const f32x4 bia = *(const f32x4*)&bq1[mt*16 + 4*g];
        uint2 pp;
        pp.x = pack2(gelu_f(acc[mt][0]+bia[0]), gelu_f(acc[mt][1]+bia[1]));
        pp.y = pack2(gelu_f(acc[mt][2]+bia[2]), gelu_f(acc[mt][3]+bia[3]));
        *(uint2*)&H1[c*LDH + mt*16 + 4*g] = pp;
      }
    }
    // ---- N-GEMM2k -> KT[dim][row] (overlays H1), masked ----
    {
      f32x4 acc2[8];
      #pragma unroll
      for (int n2=0; n2<8; ++n2) acc2[n2] = z4;
      #pragma unroll
      for (int ks4=0; ks4<4; ++ks4){
        short8 wb[8];
        #pragma unroll
        for (int n2=0; n2<8; ++n2)
          wb[n2] = *(const short8*)&sW[(size_t)(32 + n2*4+ks4)*512 + l*8];
        SBAR();
        const short8 ah = *(const short8*)&H1[c*LDH + ks4*32 + 8*g];
        #pragma unroll
        for (int n2=0; n2<8; ++n2)
          acc2[n2] = MFMA(ah, wb[n2], acc2[n2]);
      }
      #pragma unroll
      for (int n2=0; n2<8; ++n2){
        const float bb = bq2[n2*16 + c] * INVS;
        const int r0 = rbase + 4*g;
        float v0 = (r0+0 < len) ? acc2[n2][0] + bb : 0.f;
        float v1 = (r0+1 < len) ? acc2[n2][1] + bb : 0.f;
        float v2 = (r0+2 < len) ? acc2[n2][2] + bb : 0.f;
        float v3 = (r0+3 < len) ? acc2[n2][3] + bb : 0.f;
        uint2 pp; pp.x = pack2(v0,v1); pp.y = pack2(v2,v3);
        *(uint2*)&KT[(n2*16 + c)*LDT + 4*g] = pp;
      }
    }
    // ---- kv accumulate: D(16x16) += K^T(16rows) * V ; rows 16-31 zeroed ----
    {
      f32x4 kvacc[8];
      #pragma unroll
      for (int h=0; h<8; ++h) kvacc[h] = z4;
      #pragma unroll
      for (int h=0; h<8; ++h){
        const short8 kaL = *(const short8*)&KT[(h*16 + c)*LDT + 8*(g&1)];
        const short8 vbL = *(const short8*)&VT[(h*8 + (c&7))*LDT + 8*(g&1)];
        const short8 ka = (g < 2) ? kaL : zf;
        const short8 vb = (c < 8 && g < 2) ? vbL : zf;
        kvacc[h] = MFMA(ka, vb, kvacc[h]);
      }
      if (c < 8){
        float* kvg = kvgr + ((size_t)rep*16 + b)*1024;
        #pragma unroll
        for (int h=0; h<8; ++h){
          #pragma unroll
          for (int r=0; r<4; ++r)
            atomicAdd(&kvg[(h*16 + 4*g + r)*8 + c], kvacc[h][r]);
        }
      }
    }
  }
}

// ---- mid: sum replicas, build M_b = Wq2_scaled * kv_b / len (frag-linear) ----
__global__ void dk_mid(const float* __restrict__ kvgr, int nrep,
                       const int* __restrict__ vlen,
                       const float* __restrict__ bq2,
                       const u16* __restrict__ wt,
                       u16* __restrict__ Mt, float* __restrict__ c0g)
{
  __shared__ float kvs[1024];
  const int b = blockIdx.x, t = threadIdx.x;
  const float inv_len = 1.0f / (float)vlen[b];
  #pragma unroll
  for (int k=0; k<4; ++k){
    const int idx = t + 256*k;
    float s = 0.f;
    for (int r=0; r<nrep; ++r) s += kvgr[((size_t)r*16 + b)*1024 + idx];
    kvs[idx] = s * inv_len;
  }
  __syncthreads();
  for (int k=0; k<32; ++k){
    const int o = t + 256*k;           // o < 8192
    const int e = o >> 7, j = o & 127;
    const int h = e >> 3, e8 = e & 7;
    const int ks4 = j >> 5, gg = (j >> 3) & 3, el = j & 7;
    float s = 0.f;
    #pragma unroll
    for (int d=0; d<16; ++d){
      const int od = h*16 + d;         // Wq2 chunk 32 + (od>>4)*4 + ks4
      const u16 wv = wt[16384 + (((od>>4)*4 + ks4)*64 + gg*16 + (od&15))*8 + el];
      s += b2f(wv) * kvs[h*128 + d*8 + e8];
    }
    const int n3 = e >> 4, cc = e & 15;
    Mt[(size_t)b*8192 + ((n3*4 + ks4)*64 + gg*16 + cc)*8 + el] = bfc(s);
  }
  if (t < 64){
    const int e = t, h = e >> 3, e8 = e & 7;
    float s = 0.f;
    #pragma unroll
    for (int d=0; d<16; ++d)
      s += bq2[h*16+d] * INVS * kvs[h*128 + d*8 + e8];
    c0g[b*64 + e] = s;
  }
}

// ---- stage 2: persistent 8-wave blocks; Wq1 (32KB) in LDS; 16-row units ----
__global__ __launch_bounds__(512, 4) void dk_stage2(
    const float* __restrict__ qsp, const float* __restrict__ qssp,
    const float* __restrict__ bq1,
    const float* __restrict__ lnw_g, const float* __restrict__ lnb_g,
    const u16* __restrict__ wt, const u16* __restrict__ Mt,
    const float* __restrict__ c0g, float* __restrict__ outp)
{
  __shared__ u16 sH1[8][2176];         // per-wave H1 (4352B); f32[16][68] later
  __shared__ u16 sW[16384];            // 32KB Wq1, chunk ch at sW+ch*512
  const int tid = threadIdx.x;
  const int w = tid >> 6, l = tid & 63;
  const int c = l & 15, g = l >> 4;
  u16* H1 = sH1[w];
  const f32x4 z4 = {0.f,0.f,0.f,0.f};

  // stage Wq1 chunks 0-31 (4 DMA per wave)
  #pragma unroll
  for (int j=0; j<4; ++j){
    const int ch = w*4 + j;
    gld_lds16(wt + ((size_t)ch*64 + l)*8, &sW[(size_t)ch*512]);
  }
  __syncthreads();

  for (int u = blockIdx.x*8 + w; u < 8192; u += gridDim.x*8){
    const int b  = u >> 9;             // 512 units per batch
    const int ju = u & 511;
    const int rbase = ju*16;
    const size_t row0 = (size_t)b*8192 + rbase;
    const u16* Mb = Mt + (size_t)b*8192;

    // ---- T-GEMM1q, 8 x-loads pinned ----
    {
      f32x4 xqf[8];
      #pragma unroll
      for (int ks4=0; ks4<4; ++ks4){
        const int kk = ks4*32 + 8*g;
        const float* src = (ks4 < 2) ? (qssp + (row0 + c)*64 + kk)
                                     : (qsp  + (row0 + c)*64 + (kk - 64));
        xqf[ks4*2+0] = *(const f32x4*)src;
        xqf[ks4*2+1] = *(const f32x4*)(src+4);
      }
      SBAR();
      short8 xq[4];
      #pragma unroll
      for (int ks4=0; ks4<4; ++ks4)
        xq[ks4] = cvt8(xqf[ks4*2+0], xqf[ks4*2+1]);
      f32x4 acc[8];
      #pragma unroll
      for (int mt=0; mt<8; ++mt) acc[mt] = z4;
      #pragma unroll
      for (int ks4=0; ks4<4; ++ks4){
        short8 wa[8];
        #pragma unroll
        for (int mt=0; mt<8; ++mt)
          wa[mt] = *(const short8*)&sW[(size_t)(mt*4+ks4)*512 + l*8];
        SBAR();
        #pragma unroll
        for (int mt=0; mt<8; ++mt)
          acc[mt] = MFMA(wa[mt], xq[ks4], acc[mt]);
      }
      #pragma unroll
      for (int mt=0; mt<8; ++mt){
        const f32x4 bia = *(const f32x4*)&bq1[mt*16 + 4*g];
        uint2 pp;
        pp.x = pack2(gelu_f(acc[mt][0]+bia[0]), gelu_f(acc[mt][1]+bia[1]));
        pp.y = pack2(gelu_f(acc[mt][2]+bia[2]), gelu_f(acc[mt][3]+bia[3]));
        *(uint2*)&H1[c*LDH + mt*16 + 4*g] = pp;
      }
    }
    // ---- GEMMM: ctx = gh1 * M_b ; 16 M-fragment loads pinned ----
    f32x4 acc3[4];
    #pragma unroll
    for (int n3=0; n3<4; ++n3) acc3[n3] = z4;
    {
      short8 bm[16];
      #pragma unroll
      for (int ks4=0; ks4<4; ++ks4)
        #pragma unroll
        for (int n3=0; n3<4; ++n3)
          bm[ks4*4+n3] = *(const short8*)&Mb[((n3*4+ks4)*64 + l)*8];
      SBAR();
      #pragma unroll
      for (int ks4=0; ks4<4; ++ks4){
        const short8 aq = *(const short8*)&H1[c*LDH + ks4*32 + 8*g];
        #pragma unroll
        for (int n3=0; n3<4; ++n3)
          acc3[n3] = MFMA(aq, bm[ks4*4+n3], acc3[n3]);
      }
    }
    float c0v[4];
    #pragma unroll
    for (int n3=0; n3<4; ++n3) c0v[n3] = c0g[b*64 + n3*16 + c];
    // ---- LayerNorm over 64 -> LDS transpose (f32 [16][68]) ----
    float lnw[4], lnb[4];
    #pragma unroll
    for (int n3=0; n3<4; ++n3){ lnw[n3] = lnw_g[n3*16 + c]; lnb[n3] = lnb_g[n3*16 + c]; }
    float* Tb = (float*)H1;            // H1 dead after GEMMM reads
    #pragma unroll
    for (int r=0; r<4; ++r){
      float s1 = 0.f, s2 = 0.f;
      #pragma unroll
      for (int n3=0; n3<4; ++n3){
        float v = acc3[n3][r] + c0v[n3];
        s1 += v; s2 += v*v;
      }
      #pragma unroll
      for (int m=1; m<16; m<<=1){
        s1 += __shfl_xor(s1, m, 64);
        s2 += __shfl_xor(s2, m, 64);
      }
      const float mu = s1 * (1.0f/64.0f);
      const float var = s2 * (1.0f/64.0f) - mu*mu;
      const float rs = rsqrtf(var + 1e-6f);
      const int rloc = 4*g + r;
      #pragma unroll
      for (int n3=0; n3<4; ++n3)
        Tb[rloc*68 + n3*16 + c] = (acc3[n3][r] + c0v[n3] - mu)*rs*lnw[n3] + lnb[n3];
    }
    // ---- coalesced store: 4 x f32x4, 1KB contiguous per instruction ----
    float* ob = outp + row0*64;
    #pragma unroll
    for (int i=0; i<4; ++i){
      const int row = i*4 + (l>>4);
      const f32x4 vv = *(const f32x4*)&Tb[row*68 + (l&15)*4];
      *(f32x4*)(ob + row*64 + (l&15)*4) = vv;
    }
  }
}

extern "C" void kernel_launch(void* const* d_in, const int* in_sizes, int n_in,
                              void* d_out, int out_size, void* d_ws, size_t ws_size,
                              hipStream_t stream)
{
  const float* qs   = (const float*)d_in[0];
  const float* ks   = (const float*)d_in[1];
  const float* vs   = (const float*)d_in[2];
  const float* qs_s = (const float*)d_in[3];
  const float* ks_s = (const float*)d_in[4];
  const int*   vl   = (const int*)d_in[5];
  const float* Wq1  = (const float*)d_in[6];
  const float* bq1  = (const float*)d_in[7];
  const float* Wq2  = (const float*)d_in[8];
  const float* bq2  = (const float*)d_in[9];
  const float* Wv1  = (const float*)d_in[10];
  const float* bv1  = (const float*)d_in[11];
  const float* Wv2  = (const float*)d_in[12];
  const float* bv2  = (const float*)d_in[13];
  const float* lnw  = (const float*)d_in[14];
  const float* lnb  = (const float*)d_in[15];
  (void)in_sizes; (void)n_in; (void)out_size;

  // ws layout: kvgr (nrep*64KB) | wt 96KB | Mt 256KB | c0 4KB
  const size_t fixed = 96*1024 + 256*1024 + 4096;
  int nrep = 4;
  while (nrep > 1 && (size_t)nrep*65536 + fixed > ws_size) nrep >>= 1;
  float* kvgr = (float*)d_ws;
  u16*   wt   = (u16*)((char*)d_ws + (size_t)nrep*65536);
  u16*   Mt   = (u16*)((char*)wt + 96*1024);
  float* c0   = (float*)((char*)Mt + 256*1024);

  hipMemsetAsync(kvgr, 0, (size_t)nrep*65536, stream);
  dk_prep<<<192, 256, 0, stream>>>(Wq1, Wq2, Wv1, Wv2, wt);
  dk_stage1<<<256, 512, 0, stream>>>(ks, ks_s, vs, vl, bq1, bq2, bv1, bv2,
                                     wt, kvgr, nrep - 1);
  dk_mid<<<16, 256, 0, stream>>>(kvgr, nrep, vl, bq2, wt, Mt, c0);
  dk_stage2<<<512, 512, 0, stream>>>(qs, qs_s, bq1, lnw, lnb, wt, Mt, c0,
                                     (float*)d_out);
}

// Round 17
// 96.913 us; speedup vs baseline: 1.1508x; 1.1508x over previous
//
#include <hip/hip_runtime.h>
#include <hip/hip_bf16.h>

// DeepKernelAttention: linear attention with MLP feature maps.
// R17: R15 (best, 89.8us) + per-wave critical-path cuts. At 1 wave/SIMD all
// stalls are exposed, so: (1) v+k x-loads merged into ONE pinned 24-load
// group per unit (one VMEM drain, not two); (2) SBAR fences removed from LDS
// weight-fragment reads (compiler pipelines ds_read across MFMA phases);
// (3) stage2: xq+M merged into one group, sW reads unfenced.

typedef __attribute__((ext_vector_type(8))) short short8;
typedef __attribute__((ext_vector_type(4))) float f32x4;
typedef unsigned int u32;
typedef unsigned short u16;

#define MFMA(A,B,C) __builtin_amdgcn_mfma_f32_16x16x32_bf16((A),(B),(C),0,0,0)
#define SBAR() __builtin_amdgcn_sched_barrier(0)

#define LDH 136   // H1 leading dim; 272B row, 16B aligned
#define LDT 40    // KT/VT leading dim; 80B row, 16B aligned
#define INVS 0.3535533905932738f   // 64^-0.25

__device__ __forceinline__ u16 bfc(float x){
  __hip_bfloat16 h = __float2bfloat16(x);
  return __bfloat16_as_ushort(h);
}
__device__ __forceinline__ u32 pack2(float a, float b){
  return (u32)bfc(a) | ((u32)bfc(b) << 16);
}
__device__ __forceinline__ float b2f(u16 w){
  return __uint_as_float(((u32)w) << 16);
}
__device__ __forceinline__ short8 cvt8(f32x4 lo, f32x4 hi){
  short8 r;
  r[0]=(short)bfc(lo[0]); r[1]=(short)bfc(lo[1]);
  r[2]=(short)bfc(lo[2]); r[3]=(short)bfc(lo[3]);
  r[4]=(short)bfc(hi[0]); r[5]=(short)bfc(hi[1]);
  r[6]=(short)bfc(hi[2]); r[7]=(short)bfc(hi[3]);
  return r;
}
// tanh-approx gelu
__device__ __forceinline__ float gelu_f(float x){
  float s = x*x;
  float u = x * __builtin_fmaf(s, 0.035677408136300125f, 0.7978845608028654f);
  float e = __builtin_amdgcn_exp2f(u * -2.885390081777927f);
  return x * __builtin_amdgcn_rcpf(1.0f + e);
}
// direct global->LDS DMA: uniform LDS base, HW adds lane*16B
__device__ __forceinline__ void gld_lds16(const u16* gsrc, u16* ldst){
  __builtin_amdgcn_global_load_lds(
      (const __attribute__((address_space(1))) void*)gsrc,
      (__attribute__((address_space(3))) void*)ldst, 16, 0, 0);
}

// ---- weight prep: fragment-linear bf16 layout (R4/R10 ordering) ----
// chunks 0-31 Wq1 (mt*4+ks4) | 32-63 Wq2*INVS (n2*4+ks4) | 64-79 Wv1
// (mt*2+ks2) | 80-95 Wv2 (n2*4+ks4). chunk c, lane l, elem e at wt[(c*64+l)*8+e].
__global__ void dk_prep(const float* __restrict__ Wq1, const float* __restrict__ Wq2,
                        const float* __restrict__ Wv1, const float* __restrict__ Wv2,
                        u16* __restrict__ wt){
  int i = blockIdx.x*256 + threadIdx.x;   // grid 192*256 = 49152 exact
  int e = i & 7;
  int lane = (i >> 3) & 63;
  int chunk = i >> 9;
  int c = lane & 15, g = lane >> 4;
  int k0 = 8*g + e;
  float v;
  if (chunk < 32){
    int mt = chunk >> 2, ks4 = chunk & 3;
    v = Wq1[(ks4*32 + k0)*128 + mt*16 + c];
  } else if (chunk < 64){
    int ch = chunk - 32; int mt = ch >> 2, ks4 = ch & 3;
    v = Wq2[(ks4*32 + k0)*128 + mt*16 + c] * INVS;
  } else if (chunk < 80){
    int ch = chunk - 64; int mt = ch >> 1, ks2 = ch & 1;
    v = Wv1[(ks2*32 + k0)*128 + mt*16 + c];
  } else {
    int ch = chunk - 80; int n2 = ch >> 2, ks4 = ch & 3;
    v = Wv2[(ks4*32 + k0)*64 + n2*16 + c];
  }
  wt[i] = bfc(v);
}

// ---- stage 1: persistent 4-wave blocks; 96KB weights in LDS ----
__global__ __launch_bounds__(256, 1) void dk_stage1(
    const float* __restrict__ ksp, const float* __restrict__ kssp,
    const float* __restrict__ vsp, const int* __restrict__ vlen,
    const float* __restrict__ bq1, const float* __restrict__ bq2,
    const float* __restrict__ bv1, const float* __restrict__ bv2,
    const u16* __restrict__ wt, float* __restrict__ kvgr, int repmask)
{
  __shared__ u16 sA[4][5120];   // per-wave: H1 (8704B) / KT (10240B) overlay
  __shared__ u16 sB[4][2560];   // per-wave: VT (5120B)
  __shared__ u16 sW[49152];     // 96KB: all weights, chunk ch at sW+ch*512
  const int tid = threadIdx.x;
  const int w = tid >> 6, l = tid & 63;
  const int c = l & 15, g = l >> 4;

  // stage all 96 weight chunks once (24 DMA per wave, zero VGPR)
  #pragma unroll
  for (int j=0; j<24; ++j){
    const int ch = w*24 + j;
    gld_lds16(wt + ((size_t)ch*64 + l)*8, &sW[(size_t)ch*512]);
  }

  // lane-parallel inclusive prefix of 32-row unit counts over 16 batches
  int pfx = (l < 16) ? ((vlen[l] + 31) >> 5) : 0;
  #pragma unroll
  for (int m=1; m<16; m<<=1){
    int v = __shfl_up(pfx, m, 64);
    if (l >= m) pfx += v;
  }
  const int T = __shfl(pfx, 15, 64);
  __syncthreads();                     // weights resident

  u16* H1 = sA[w];
  u16* KT = sA[w];                     // overlay (H1 dead after GEMM2 reads)
  u16* VT = sB[w];
  const f32x4 z4 = {0.f,0.f,0.f,0.f};

  for (int u = blockIdx.x*4 + w; u < T; u += gridDim.x*4){
    unsigned long long mk = __ballot(l < 16 && pfx <= u);
    const int b = __popcll(mk);
    const int ju = u - (b ? __shfl(pfx, b-1, 64) : 0);
    const int len = vlen[b];
    const int rbase = ju*32;
    const int rep = u & repmask;
    const size_t row0 = (size_t)b*8192 + rbase;

    // ---- ONE pinned load group: all v + k x-loads for this unit ----
    f32x4 xvf[8];
    f32x4 xkf[16];
    #pragma unroll
    for (int ks2=0; ks2<2; ++ks2){
      #pragma unroll
      for (int nt=0; nt<2; ++nt){
        const float* src = vsp + (row0 + nt*16 + c)*64 + ks2*32 + 8*g;
        xvf[(ks2*2+nt)*2+0] = *(const f32x4*)src;
        xvf[(ks2*2+nt)*2+1] = *(const f32x4*)(src+4);
      }
    }
    #pragma unroll
    for (int ks4=0; ks4<4; ++ks4){
      #pragma unroll
      for (int nt=0; nt<2; ++nt){
        const int kk = ks4*32 + 8*g;
        const float* src = (ks4 < 2) ? (kssp + (row0 + nt*16 + c)*64 + kk)
                                     : (ksp  + (row0 + nt*16 + c)*64 + (kk - 64));
        xkf[(ks4*2+nt)*2+0] = *(const f32x4*)src;
        xkf[(ks4*2+nt)*2+1] = *(const f32x4*)(src+4);
      }
    }
    SBAR();                            // pin VMEM group; single drain below

    // ---- v chain: T-GEMM1v (K=64) ----
    {
      short8 xv[2][2];
      #pragma unroll
      for (int ks2=0; ks2<2; ++ks2)
        #pragma unroll
        for (int nt=0; nt<2; ++nt)
          xv[ks2][nt] = cvt8(xvf[(ks2*2+nt)*2+0], xvf[(ks2*2+nt)*2+1]);
      f32x4 av[8][2];
      #pragma unroll
      for (int mt=0; mt<8; ++mt){ av[mt][0]=z4; av[mt][1]=z4; }
      #pragma unroll
      for (int ks2=0; ks2<2; ++ks2){
        short8 wa[8];
        #pragma unroll
        for (int mt=0; mt<8; ++mt)
          wa[mt] = *(const short8*)&sW[(size_t)(64 + mt*2+ks2)*512 + l*8];
        #pragma unroll
        for (int mt=0; mt<8; ++mt){
          av[mt][0] = MFMA(wa[mt], xv[ks2][0], av[mt][0]);
          av[mt][1] = MFMA(wa[mt], xv[ks2][1], av[mt][1]);
        }
      }
      #pragma unroll
      for (int mt=0; mt<8; ++mt){
        const f32x4 bia = *(const f32x4*)&bv1[mt*16 + 4*g];
        #pragma unroll
        for (int nt=0; nt<2; ++nt){
          uint2 pp;
          pp.x = pack2(gelu_f(av[mt][nt][0]+bia[0]), gelu_f(av[mt][nt][1]+bia[1]));
          pp.y = pack2(gelu_f(av[mt][nt][2]+bia[2]), gelu_f(av[mt][nt][3]+bia[3]));
          *(uint2*)&H1[(nt*16 + c)*LDH + mt*16 + 4*g] = pp;
        }
      }
    }
    // ---- N-GEMM2v: N=64 -> VT[dim][row] ----
    {
      f32x4 acv[2][4];
      #pragma unroll
      for (int n2=0; n2<4; ++n2){ acv[0][n2]=z4; acv[1][n2]=z4; }
      #pragma unroll
      for (int ks4=0; ks4<4; ++ks4){
        short8 wb[4];
        #pragma unroll
        for (int n2=0; n2<4; ++n2)
          wb[n2] = *(const short8*)&sW[(size_t)(80 + n2*4+ks4)*512 + l*8];
        const short8 ah0 = *(const short8*)&H1[(c     )*LDH + ks4*32 + 8*g];
        const short8 ah1 = *(const short8*)&H1[(16 + c)*LDH + ks4*32 + 8*g];
        #pragma unroll
        for (int n2=0; n2<4; ++n2){
          acv[0][n2] = MFMA(ah0, wb[n2], acv[0][n2]);
          acv[1][n2] = MFMA(ah1, wb[n2], acv[1][n2]);
        }
      }
      #pragma unroll
      for (int n2=0; n2<4; ++n2){
        const float bb = bv2[n2*16 + c];
        #pragma unroll
        for (int mt=0; mt<2; ++mt){
          uint2 pp;
          pp.x = pack2(acv[mt][n2][0]+bb, acv[mt][n2][1]+bb);
          pp.y = pack2(acv[mt][n2][2]+bb, acv[mt][n2][3]+bb);
          *(uint2*)&VT[(n2*16+c)*LDT + mt*16 + 4*g] = pp;
        }
      }
    }
    // ---- k chain: T-GEMM1k (x already in regs) ----
    {
      short8 xk[4][2];
      #pragma unroll
      for (int ks4=0; ks4<4; ++ks4)
        #pragma unroll
        for (int nt=0; nt<2; ++nt)
          xk[ks4][nt] = cvt8(xkf[(ks4*2+nt)*2+0], xkf[(ks4*2+nt)*2+1]);
      f32x4 acc[8][2];
      #pragma unroll
      for (int mt=0; mt<8; ++mt){ acc[mt][0]=z4; acc[mt][1]=z4; }
      #pragma unroll
      for (int ks4=0; ks4<4; ++ks4){
        short8 wa[8];
        #pragma unroll
        for (int mt=0; mt<8; ++mt)
          wa[mt] = *(const short8*)&sW[(size_t)(mt*4+ks4)*512 + l*8];
        #pragma unroll
        for (int mt=0; mt<8; ++mt){
          acc[mt][0] = MFMA(wa[mt], xk[ks4][0], acc[mt][0]);
          acc[mt][1] = MFMA(wa[mt], xk[ks4][1], acc[mt][1]);
        }
      }
      #pragma unroll
      for (int mt=0; mt<8; ++mt){
        const f32x4 bia = *(const f32x4*)&bq1[mt*16 + 4*g];
        #pragma unroll
        for (int nt=0; nt<2; ++nt){
          uint2 pp;
          pp.x = pack2(gelu_f(acc[mt][nt][0]+bia[0]), gelu_f(acc[mt][nt][1]+bia[1]));
          pp.y = pack2(gelu_f(acc[mt][nt][2]+bia[2]), gelu_f(acc[mt][nt][3]+bia[3]));
          *(uint2*)&H1[(nt*16 + c)*LDH + mt*16 + 4*g] = pp;
        }
      }
    }
    // ---- N-GEMM2k -> KT[dim][row] (overlays H1), masked ----
    {
      f32x4 acc2[2][8];
      #pragma unroll
      for (int n2=0; n2<8; ++n2){ acc2[0][n2]=z4; acc2[1][n2]=z4; }
      #pragma unroll
      for (int ks4=0; ks4<4; ++ks4){
        short8 wb[8];
        #pragma unroll
        for (int n2=0; n2<8; ++n2)
          wb[n2] = *(const short8*)&sW[(size_t)(32 + n2*4+ks4)*512 + l*8];
        const short8 ah0 = *(const short8*)&H1[(c     )*LDH + ks4*32 + 8*g];
        const short8 ah1 = *(const short8*)&H1[(16 + c)*LDH + ks4*32 + 8*g];
        #pragma unroll
        for (int n2=0; n2<8; ++n2){
          acc2[0][n2] = MFMA(ah0, wb[n2], acc2[0][n2]);
          acc2[1][n2] = MFMA(ah1, wb[n2], acc2[1][n2]);
        }
      }
      #pragma unroll
      for (int n2=0; n2<8; ++n2){
        const float bb = bq2[n2*16 + c] * INVS;
        #pragma unroll
        for (int mt=0; mt<2; ++mt){
          const int r0 = rbase + mt*16 + 4*g;
          float v0 = (r0+0 < len) ? acc2[mt][n2][0] + bb : 0.f;
          float v1 = (r0+1 < len) ? acc2[mt][n2][1] + bb : 0.f;
          float v2 = (r0+2 < len) ? acc2[mt][n2][2] + bb : 0.f;
          float v3 = (r0+3 < len) ? acc2[mt][n2][3] + bb : 0.f;
          uint2 pp; pp.x = pack2(v0,v1); pp.y = pack2(v2,v3);
          *(uint2*)&KT[(n2*16 + c)*LDT + mt*16 + 4*g] = pp;
        }
      }
    }
    // ---- kv accumulate: per head, D(16x16) += K^T * V ----
    {
      short8 zf = {0,0,0,0,0,0,0,0};
      f32x4 kvacc[8];
      #pragma unroll
      for (int h=0; h<8; ++h) kvacc[h] = z4;
      #pragma unroll
      for (int h=0; h<8; ++h){
        const short8 ka = *(const short8*)&KT[(h*16 + c)*LDT + 8*g];
        short8 vb = zf;
        if (c < 8) vb = *(const short8*)&VT[(h*8 + c)*LDT + 8*g];
        kvacc[h] = MFMA(ka, vb, kvacc[h]);
      }
      if (c < 8){
        float* kvg = kvgr + ((size_t)rep*16 + b)*1024;
        #pragma unroll
        for (int h=0; h<8; ++h){
          #pragma unroll
          for (int r=0; r<4; ++r)
            atomicAdd(&kvg[(h*16 + 4*g + r)*8 + c], kvacc[h][r]);
        }
      }
    }
  }
}

// ---- mid: sum replicas, build M_b = Wq2_scaled * kv_b / len (frag-linear) ----
__global__ void dk_mid(const float* __restrict__ kvgr, int nrep,
                       const int* __restrict__ vlen,
                       const float* __restrict__ bq2,
                       const u16* __restrict__ wt,
                       u16* __restrict__ Mt, float* __restrict__ c0g)
{
  __shared__ float kvs[1024];
  const int b = blockIdx.x, t = threadIdx.x;
  const float inv_len = 1.0f / (float)vlen[b];
  #pragma unroll
  for (int k=0; k<4; ++k){
    const int idx = t + 256*k;
    float s = 0.f;
    for (int r=0; r<nrep; ++r) s += kvgr[((size_t)r*16 + b)*1024 + idx];
    kvs[idx] = s * inv_len;
  }
  __syncthreads();
  for (int k=0; k<32; ++k){
    const int o = t + 256*k;           // o < 8192
    const int e = o >> 7, j = o & 127;
    const int h = e >> 3, e8 = e & 7;
    const int ks4 = j >> 5, gg = (j >> 3) & 3, el = j & 7;
    float s = 0.f;
    #pragma unroll
    for (int d=0; d<16; ++d){
      const int od = h*16 + d;         // Wq2 chunk 32 + (od>>4)*4 + ks4
      const u16 wv = wt[16384 + (((od>>4)*4 + ks4)*64 + gg*16 + (od&15))*8 + el];
      s += b2f(wv) * kvs[h*128 + d*8 + e8];
    }
    const int n3 = e >> 4, cc = e & 15;
    Mt[(size_t)b*8192 + ((n3*4 + ks4)*64 + gg*16 + cc)*8 + el] = bfc(s);
  }
  if (t < 64){
    const int e = t, h = e >> 3, e8 = e & 7;
    float s = 0.f;
    #pragma unroll
    for (int d=0; d<16; ++d)
      s += bq2[h*16+d] * INVS * kvs[h*128 + d*8 + e8];
    c0g[b*64 + e] = s;
  }
}

// ---- stage 2: persistent 4-wave blocks; Wq1 (32KB) in LDS ----
__global__ __launch_bounds__(256, 2) void dk_stage2(
    const float* __restrict__ qsp, const float* __restrict__ qssp,
    const float* __restrict__ bq1,
    const float* __restrict__ lnw_g, const float* __restrict__ lnb_g,
    const u16* __restrict__ wt, const u16* __restrict__ Mt,
    const float* __restrict__ c0g, float* __restrict__ outp)
{
  __shared__ u16 sH1[4][32*LDH];       // per-wave H1 (8704B); f32[32][68] later
  __shared__ u16 sW[16384];            // 32KB Wq1, chunk ch at sW+ch*512
  const int tid = threadIdx.x;
  const int w = tid >> 6, l = tid & 63;
  const int c = l & 15, g = l >> 4;
  u16* H1 = sH1[w];
  const f32x4 z4 = {0.f,0.f,0.f,0.f};

  // stage Wq1 chunks 0-31 (8 DMA per wave)
  #pragma unroll
  for (int j=0; j<8; ++j){
    const int ch = w*8 + j;
    gld_lds16(wt + ((size_t)ch*64 + l)*8, &sW[(size_t)ch*512]);
  }
  __syncthreads();

  for (int u = blockIdx.x*4 + w; u < 4096; u += gridDim.x*4){
    const int b  = u >> 8;
    const int ju = u & 255;
    const int rbase = ju*32;
    const size_t row0 = (size_t)b*8192 + rbase;
    const u16* Mb = Mt + (size_t)b*8192;

    // ---- ONE pinned load group: all xq + M fragments ----
    f32x4 xqf[16];
    short8 bm[16];
    #pragma unroll
    for (int ks4=0; ks4<4; ++ks4){
      #pragma unroll
      for (int nt=0; nt<2; ++nt){
        const int kk = ks4*32 + 8*g;
        const float* src = (ks4 < 2) ? (qssp + (row0 + nt*16 + c)*64 + kk)
                                     : (qsp  + (row0 + nt*16 + c)*64 + (kk - 64));
        xqf[(ks4*2+nt)*2+0] = *(const f32x4*)src;
        xqf[(ks4*2+nt)*2+1] = *(const f32x4*)(src+4);
      }
    }
    #pragma unroll
    for (int ks4=0; ks4<4; ++ks4)
      #pragma unroll
      for (int n3=0; n3<4; ++n3)
        bm[ks4*4+n3] = *(const short8*)&Mb[((n3*4+ks4)*64 + l)*8];
    SBAR();

    // ---- T-GEMM1q ----
    {
      short8 xq[4][2];
      #pragma unroll
      for (int ks4=0; ks4<4; ++ks4)
        #pragma unroll
        for (int nt=0; nt<2; ++nt)
          xq[ks4][nt] = cvt8(xqf[(ks4*2+nt)*2+0], xqf[(ks4*2+nt)*2+1]);
      f32x4 acc[8][2];
      #pragma unroll
      for (int mt=0; mt<8; ++mt){ acc[mt][0]=z4; acc[mt][1]=z4; }
      #pragma unroll
      for (int ks4=0; ks4<4; ++ks4){
        short8 wa[8];
        #pragma unroll
        for (int mt=0; mt<8; ++mt)
          wa[mt] = *(const short8*)&sW[(size_t)(mt*4+ks4)*512 + l*8];
        #pragma unroll
        for (int mt=0; mt<8; ++mt){
          acc[mt][0] = MFMA(wa[mt], xq[ks4][0], acc[mt][0]);
          acc[mt][1] = MFMA(wa[mt], xq[ks4][1], acc[mt][1]);
        }
      }
      #pragma unroll
      for (int mt=0; mt<8; ++mt){
        const f32x4 bia = *(const f32x4*)&bq1[mt*16 + 4*g];
        #pragma unroll
        for (int nt=0; nt<2; ++nt){
          uint2 pp;
          pp.x = pack2(gelu_f(acc[mt][nt][0]+bia[0]), gelu_f(acc[mt][nt][1]+bia[1]));
          pp.y = pack2(gelu_f(acc[mt][nt][2]+bia[2]), gelu_f(acc[mt][nt][3]+bia[3]));
          *(uint2*)&H1[(nt*16 + c)*LDH + mt*16 + 4*g] = pp;
        }
      }
    }
    // ---- GEMMM: ctx = gh1 * M_b (bm already in regs) ----
    f32x4 acc3[2][4];
    #pragma unroll
    for (int n3=0; n3<4; ++n3){ acc3[0][n3]=z4; acc3[1][n3]=z4; }
    #pragma unroll
    for (int ks4=0; ks4<4; ++ks4){
      const short8 aq0 = *(const short8*)&H1[(c     )*LDH + ks4*32 + 8*g];
      const short8 aq1 = *(const short8*)&H1[(16 + c)*LDH + ks4*32 + 8*g];
      #pragma unroll
      for (int n3=0; n3<4; ++n3){
        acc3[0][n3] = MFMA(aq0, bm[ks4*4+n3], acc3[0][n3]);
        acc3[1][n3] = MFMA(aq1, bm[ks4*4+n3], acc3[1][n3]);
      }
    }
    float c0v[4];
    #pragma unroll
    for (int n3=0; n3<4; ++n3) c0v[n3] = c0g[b*64 + n3*16 + c];
    // ---- LayerNorm over 64 -> LDS transpose (f32 [32][68]) ----
    float lnw[4], lnb[4];
    #pragma unroll
    for (int n3=0; n3<4; ++n3){ lnw[n3] = lnw_g[n3*16 + c]; lnb[n3] = lnb_g[n3*16 + c]; }
    float* Tb = (float*)H1;            // H1 dead after GEMMM reads
    #pragma unroll
    for (int mt=0; mt<2; ++mt){
      #pragma unroll
      for (int r=0; r<4; ++r){
        float s1 = 0.f, s2 = 0.f;
        #pragma unroll
        for (int n3=0; n3<4; ++n3){
          float v = acc3[mt][n3][r] + c0v[n3];
          s1 += v; s2 += v*v;
        }
        #pragma unroll
        for (int m=1; m<16; m<<=1){
          s1 += __shfl_xor(s1, m, 64);
          s2 += __shfl_xor(s2, m, 64);
        }
        const float mu = s1 * (1.0f/64.0f);
        const float var = s2 * (1.0f/64.0f) - mu*mu;
        const float rs = rsqrtf(var + 1e-6f);
        const int rloc = mt*16 + 4*g + r;
        #pragma unroll
        for (int n3=0; n3<4; ++n3)
          Tb[rloc*68 + n3*16 + c] = (acc3[mt][n3][r] + c0v[n3] - mu)*rs*lnw[n3] + lnb[n3];
      }
    }
    // ---- coalesced store: 8 x f32x4 ----
    float* ob = outp + row0*64;
    #pragma unroll
    for (int i=0; i<8; ++i){
      const int row = i*4 + (l>>4);
      const f32x4 vv = *(const f32x4*)&Tb[row*68 + (l&15)*4];
      *(f32x4*)(ob + row*64 + (l&15)*4) = vv;
    }
  }
}

extern "C" void kernel_launch(void* const* d_in, const int* in_sizes, int n_in,
                              void* d_out, int out_size, void* d_ws, size_t ws_size,
                              hipStream_t stream)
{
  const float* qs   = (const float*)d_in[0];
  const float* ks   = (const float*)d_in[1];
  const float* vs   = (const float*)d_in[2];
  const float* qs_s = (const float*)d_in[3];
  const float* ks_s = (const float*)d_in[4];
  const int*   vl   = (const int*)d_in[5];
  const float* Wq1  = (const float*)d_in[6];
  const float* bq1  = (const float*)d_in[7];
  const float* Wq2  = (const float*)d_in[8];
  const float* bq2  = (const float*)d_in[9];
  const float* Wv1  = (const float*)d_in[10];
  const float* bv1  = (const float*)d_in[11];
  const float* Wv2  = (const float*)d_in[12];
  const float* bv2  = (const float*)d_in[13];
  const float* lnw  = (const float*)d_in[14];
  const float* lnb  = (const float*)d_in[15];
  (void)in_sizes; (void)n_in; (void)out_size;

  // ws layout: kvgr (nrep*64KB) | wt 96KB | Mt 256KB | c0 4KB
  const size_t fixed = 96*1024 + 256*1024 + 4096;
  int nrep = 4;
  while (nrep > 1 && (size_t)nrep*65536 + fixed > ws_size) nrep >>= 1;
  float* kvgr = (float*)d_ws;
  u16*   wt   = (u16*)((char*)d_ws + (size_t)nrep*65536);
  u16*   Mt   = (u16*)((char*)wt + 96*1024);
  float* c0   = (float*)((char*)Mt + 256*1024);

  hipMemsetAsync(kvgr, 0, (size_t)nrep*65536, stream);
  dk_prep<<<192, 256, 0, stream>>>(Wq1, Wq2, Wv1, Wv2, wt);
  dk_stage1<<<256, 256, 0, stream>>>(ks, ks_s, vs, vl, bq1, bq2, bv1, bv2,
                                     wt, kvgr, nrep - 1);
  dk_mid<<<16, 256, 0, stream>>>(kvgr, nrep, vl, bq2, wt, Mt, c0);
  dk_stage2<<<512, 256, 0, stream>>>(qs, qs_s, bq1, lnw, lnb, wt, Mt, c0,
                                     (float*)d_out);
}

// Round 18
// 89.234 us; speedup vs baseline: 1.2498x; 1.0861x over previous
//
#include <hip/hip_runtime.h>
#include <hip/hip_bf16.h>

// DeepKernelAttention: linear attention with MLP feature maps.
// R18: stage1 = R17 (merged v+k pinned load group, unfenced sW ds_reads —
// neutral-to-positive). stage2 = R15's split-group no-spill form (xqf group
// dies into GEMM1q BEFORE bm group loads; R17's merge spilled +15MB scratch)
// with R17's unfenced sW reads kept. Only VMEM groups are SBAR-pinned.

typedef __attribute__((ext_vector_type(8))) short short8;
typedef __attribute__((ext_vector_type(4))) float f32x4;
typedef unsigned int u32;
typedef unsigned short u16;

#define MFMA(A,B,C) __builtin_amdgcn_mfma_f32_16x16x32_bf16((A),(B),(C),0,0,0)
#define SBAR() __builtin_amdgcn_sched_barrier(0)

#define LDH 136   // H1 leading dim; 272B row, 16B aligned
#define LDT 40    // KT/VT leading dim; 80B row, 16B aligned
#define INVS 0.3535533905932738f   // 64^-0.25

__device__ __forceinline__ u16 bfc(float x){
  __hip_bfloat16 h = __float2bfloat16(x);
  return __bfloat16_as_ushort(h);
}
__device__ __forceinline__ u32 pack2(float a, float b){
  return (u32)bfc(a) | ((u32)bfc(b) << 16);
}
__device__ __forceinline__ float b2f(u16 w){
  return __uint_as_float(((u32)w) << 16);
}
__device__ __forceinline__ short8 cvt8(f32x4 lo, f32x4 hi){
  short8 r;
  r[0]=(short)bfc(lo[0]); r[1]=(short)bfc(lo[1]);
  r[2]=(short)bfc(lo[2]); r[3]=(short)bfc(lo[3]);
  r[4]=(short)bfc(hi[0]); r[5]=(short)bfc(hi[1]);
  r[6]=(short)bfc(hi[2]); r[7]=(short)bfc(hi[3]);
  return r;
}
// tanh-approx gelu
__device__ __forceinline__ float gelu_f(float x){
  float s = x*x;
  float u = x * __builtin_fmaf(s, 0.035677408136300125f, 0.7978845608028654f);
  float e = __builtin_amdgcn_exp2f(u * -2.885390081777927f);
  return x * __builtin_amdgcn_rcpf(1.0f + e);
}
// direct global->LDS DMA: uniform LDS base, HW adds lane*16B
__device__ __forceinline__ void gld_lds16(const u16* gsrc, u16* ldst){
  __builtin_amdgcn_global_load_lds(
      (const __attribute__((address_space(1))) void*)gsrc,
      (__attribute__((address_space(3))) void*)ldst, 16, 0, 0);
}

// ---- weight prep: fragment-linear bf16 layout (R4/R10 ordering) ----
__global__ void dk_prep(const float* __restrict__ Wq1, const float* __restrict__ Wq2,
                        const float* __restrict__ Wv1, const float* __restrict__ Wv2,
                        u16* __restrict__ wt){
  int i = blockIdx.x*256 + threadIdx.x;   // grid 192*256 = 49152 exact
  int e = i & 7;
  int lane = (i >> 3) & 63;
  int chunk = i >> 9;
  int c = lane & 15, g = lane >> 4;
  int k0 = 8*g + e;
  float v;
  if (chunk < 32){
    int mt = chunk >> 2, ks4 = chunk & 3;
    v = Wq1[(ks4*32 + k0)*128 + mt*16 + c];
  } else if (chunk < 64){
    int ch = chunk - 32; int mt = ch >> 2, ks4 = ch & 3;
    v = Wq2[(ks4*32 + k0)*128 + mt*16 + c] * INVS;
  } else if (chunk < 80){
    int ch = chunk - 64; int mt = ch >> 1, ks2 = ch & 1;
    v = Wv1[(ks2*32 + k0)*128 + mt*16 + c];
  } else {
    int ch = chunk - 80; int n2 = ch >> 2, ks4 = ch & 3;
    v = Wv2[(ks4*32 + k0)*64 + n2*16 + c];
  }
  wt[i] = bfc(v);
}

// ---- stage 1: persistent 4-wave blocks; 96KB weights in LDS ----
__global__ __launch_bounds__(256, 1) void dk_stage1(
    const float* __restrict__ ksp, const float* __restrict__ kssp,
    const float* __restrict__ vsp, const int* __restrict__ vlen,
    const float* __restrict__ bq1, const float* __restrict__ bq2,
    const float* __restrict__ bv1, const float* __restrict__ bv2,
    const u16* __restrict__ wt, float* __restrict__ kvgr, int repmask)
{
  __shared__ u16 sA[4][5120];   // per-wave: H1 (8704B) / KT (10240B) overlay
  __shared__ u16 sB[4][2560];   // per-wave: VT (5120B)
  __shared__ u16 sW[49152];     // 96KB: all weights, chunk ch at sW+ch*512
  const int tid = threadIdx.x;
  const int w = tid >> 6, l = tid & 63;
  const int c = l & 15, g = l >> 4;

  // stage all 96 weight chunks once (24 DMA per wave, zero VGPR)
  #pragma unroll
  for (int j=0; j<24; ++j){
    const int ch = w*24 + j;
    gld_lds16(wt + ((size_t)ch*64 + l)*8, &sW[(size_t)ch*512]);
  }

  // lane-parallel inclusive prefix of 32-row unit counts over 16 batches
  int pfx = (l < 16) ? ((vlen[l] + 31) >> 5) : 0;
  #pragma unroll
  for (int m=1; m<16; m<<=1){
    int v = __shfl_up(pfx, m, 64);
    if (l >= m) pfx += v;
  }
  const int T = __shfl(pfx, 15, 64);
  __syncthreads();                     // weights resident

  u16* H1 = sA[w];
  u16* KT = sA[w];                     // overlay (H1 dead after GEMM2 reads)
  u16* VT = sB[w];
  const f32x4 z4 = {0.f,0.f,0.f,0.f};

  for (int u = blockIdx.x*4 + w; u < T; u += gridDim.x*4){
    unsigned long long mk = __ballot(l < 16 && pfx <= u);
    const int b = __popcll(mk);
    const int ju = u - (b ? __shfl(pfx, b-1, 64) : 0);
    const int len = vlen[b];
    const int rbase = ju*32;
    const int rep = u & repmask;
    const size_t row0 = (size_t)b*8192 + rbase;

    // ---- ONE pinned load group: all v + k x-loads for this unit ----
    f32x4 xvf[8];
    f32x4 xkf[16];
    #pragma unroll
    for (int ks2=0; ks2<2; ++ks2){
      #pragma unroll
      for (int nt=0; nt<2; ++nt){
        const float* src = vsp + (row0 + nt*16 + c)*64 + ks2*32 + 8*g;
        xvf[(ks2*2+nt)*2+0] = *(const f32x4*)src;
        xvf[(ks2*2+nt)*2+1] = *(const f32x4*)(src+4);
      }
    }
    #pragma unroll
    for (int ks4=0; ks4<4; ++ks4){
      #pragma unroll
      for (int nt=0; nt<2; ++nt){
        const int kk = ks4*32 + 8*g;
        const float* src = (ks4 < 2) ? (kssp + (row0 + nt*16 + c)*64 + kk)
                                     : (ksp  + (row0 + nt*16 + c)*64 + (kk - 64));
        xkf[(ks4*2+nt)*2+0] = *(const f32x4*)src;
        xkf[(ks4*2+nt)*2+1] = *(const f32x4*)(src+4);
      }
    }
    SBAR();                            // pin VMEM group; single drain below

    // ---- v chain: T-GEMM1v (K=64) ----
    {
      short8 xv[2][2];
      #pragma unroll
      for (int ks2=0; ks2<2; ++ks2)
        #pragma unroll
        for (int nt=0; nt<2; ++nt)
          xv[ks2][nt] = cvt8(xvf[(ks2*2+nt)*2+0], xvf[(ks2*2+nt)*2+1]);
      f32x4 av[8][2];
      #pragma unroll
      for (int mt=0; mt<8; ++mt){ av[mt][0]=z4; av[mt][1]=z4; }
      #pragma unroll
      for (int ks2=0; ks2<2; ++ks2){
        short8 wa[8];
        #pragma unroll
        for (int mt=0; mt<8; ++mt)
          wa[mt] = *(const short8*)&sW[(size_t)(64 + mt*2+ks2)*512 + l*8];
        #pragma unroll
        for (int mt=0; mt<8; ++mt){
          av[mt][0] = MFMA(wa[mt], xv[ks2][0], av[mt][0]);
          av[mt][1] = MFMA(wa[mt], xv[ks2][1], av[mt][1]);
        }
      }
      #pragma unroll
      for (int mt=0; mt<8; ++mt){
        const f32x4 bia = *(const f32x4*)&bv1[mt*16 + 4*g];
        #pragma unroll
        for (int nt=0; nt<2; ++nt){
          uint2 pp;
          pp.x = pack2(gelu_f(av[mt][nt][0]+bia[0]), gelu_f(av[mt][nt][1]+bia[1]));
          pp.y = pack2(gelu_f(av[mt][nt][2]+bia[2]), gelu_f(av[mt][nt][3]+bia[3]));
          *(uint2*)&H1[(nt*16 + c)*LDH + mt*16 + 4*g] = pp;
        }
      }
    }
    // ---- N-GEMM2v: N=64 -> VT[dim][row] ----
    {
      f32x4 acv[2][4];
      #pragma unroll
      for (int n2=0; n2<4; ++n2){ acv[0][n2]=z4; acv[1][n2]=z4; }
      #pragma unroll
      for (int ks4=0; ks4<4; ++ks4){
        short8 wb[4];
        #pragma unroll
        for (int n2=0; n2<4; ++n2)
          wb[n2] = *(const short8*)&sW[(size_t)(80 + n2*4+ks4)*512 + l*8];
        const short8 ah0 = *(const short8*)&H1[(c     )*LDH + ks4*32 + 8*g];
        const short8 ah1 = *(const short8*)&H1[(16 + c)*LDH + ks4*32 + 8*g];
        #pragma unroll
        for (int n2=0; n2<4; ++n2){
          acv[0][n2] = MFMA(ah0, wb[n2], acv[0][n2]);
          acv[1][n2] = MFMA(ah1, wb[n2], acv[1][n2]);
        }
      }
      #pragma unroll
      for (int n2=0; n2<4; ++n2){
        const float bb = bv2[n2*16 + c];
        #pragma unroll
        for (int mt=0; mt<2; ++mt){
          uint2 pp;
          pp.x = pack2(acv[mt][n2][0]+bb, acv[mt][n2][1]+bb);
          pp.y = pack2(acv[mt][n2][2]+bb, acv[mt][n2][3]+bb);
          *(uint2*)&VT[(n2*16+c)*LDT + mt*16 + 4*g] = pp;
        }
      }
    }
    // ---- k chain: T-GEMM1k (x already in regs) ----
    {
      short8 xk[4][2];
      #pragma unroll
      for (int ks4=0; ks4<4; ++ks4)
        #pragma unroll
        for (int nt=0; nt<2; ++nt)
          xk[ks4][nt] = cvt8(xkf[(ks4*2+nt)*2+0], xkf[(ks4*2+nt)*2+1]);
      f32x4 acc[8][2];
      #pragma unroll
      for (int mt=0; mt<8; ++mt){ acc[mt][0]=z4; acc[mt][1]=z4; }
      #pragma unroll
      for (int ks4=0; ks4<4; ++ks4){
        short8 wa[8];
        #pragma unroll
        for (int mt=0; mt<8; ++mt)
          wa[mt] = *(const short8*)&sW[(size_t)(mt*4+ks4)*512 + l*8];
        #pragma unroll
        for (int mt=0; mt<8; ++mt){
          acc[mt][0] = MFMA(wa[mt], xk[ks4][0], acc[mt][0]);
          acc[mt][1] = MFMA(wa[mt], xk[ks4][1], acc[mt][1]);
        }
      }
      #pragma unroll
      for (int mt=0; mt<8; ++mt){
        const f32x4 bia = *(const f32x4*)&bq1[mt*16 + 4*g];
        #pragma unroll
        for (int nt=0; nt<2; ++nt){
          uint2 pp;
          pp.x = pack2(gelu_f(acc[mt][nt][0]+bia[0]), gelu_f(acc[mt][nt][1]+bia[1]));
          pp.y = pack2(gelu_f(acc[mt][nt][2]+bia[2]), gelu_f(acc[mt][nt][3]+bia[3]));
          *(uint2*)&H1[(nt*16 + c)*LDH + mt*16 + 4*g] = pp;
        }
      }
    }
    // ---- N-GEMM2k -> KT[dim][row] (overlays H1), masked ----
    {
      f32x4 acc2[2][8];
      #pragma unroll
      for (int n2=0; n2<8; ++n2){ acc2[0][n2]=z4; acc2[1][n2]=z4; }
      #pragma unroll
      for (int ks4=0; ks4<4; ++ks4){
        short8 wb[8];
        #pragma unroll
        for (int n2=0; n2<8; ++n2)
          wb[n2] = *(const short8*)&sW[(size_t)(32 + n2*4+ks4)*512 + l*8];
        const short8 ah0 = *(const short8*)&H1[(c     )*LDH + ks4*32 + 8*g];
        const short8 ah1 = *(const short8*)&H1[(16 + c)*LDH + ks4*32 + 8*g];
        #pragma unroll
        for (int n2=0; n2<8; ++n2){
          acc2[0][n2] = MFMA(ah0, wb[n2], acc2[0][n2]);
          acc2[1][n2] = MFMA(ah1, wb[n2], acc2[1][n2]);
        }
      }
      #pragma unroll
      for (int n2=0; n2<8; ++n2){
        const float bb = bq2[n2*16 + c] * INVS;
        #pragma unroll
        for (int mt=0; mt<2; ++mt){
          const int r0 = rbase + mt*16 + 4*g;
          float v0 = (r0+0 < len) ? acc2[mt][n2][0] + bb : 0.f;
          float v1 = (r0+1 < len) ? acc2[mt][n2][1] + bb : 0.f;
          float v2 = (r0+2 < len) ? acc2[mt][n2][2] + bb : 0.f;
          float v3 = (r0+3 < len) ? acc2[mt][n2][3] + bb : 0.f;
          uint2 pp; pp.x = pack2(v0,v1); pp.y = pack2(v2,v3);
          *(uint2*)&KT[(n2*16 + c)*LDT + mt*16 + 4*g] = pp;
        }
      }
    }
    // ---- kv accumulate: per head, D(16x16) += K^T * V ----
    {
      short8 zf = {0,0,0,0,0,0,0,0};
      f32x4 kvacc[8];
      #pragma unroll
      for (int h=0; h<8; ++h) kvacc[h] = z4;
      #pragma unroll
      for (int h=0; h<8; ++h){
        const short8 ka = *(const short8*)&KT[(h*16 + c)*LDT + 8*g];
        short8 vb = zf;
        if (c < 8) vb = *(const short8*)&VT[(h*8 + c)*LDT + 8*g];
        kvacc[h] = MFMA(ka, vb, kvacc[h]);
      }
      if (c < 8){
        float* kvg = kvgr + ((size_t)rep*16 + b)*1024;
        #pragma unroll
        for (int h=0; h<8; ++h){
          #pragma unroll
          for (int r=0; r<4; ++r)
            atomicAdd(&kvg[(h*16 + 4*g + r)*8 + c], kvacc[h][r]);
        }
      }
    }
  }
}

// ---- mid: sum replicas, build M_b = Wq2_scaled * kv_b / len (frag-linear) ----
__global__ void dk_mid(const float* __restrict__ kvgr, int nrep,
                       const int* __restrict__ vlen,
                       const float* __restrict__ bq2,
                       const u16* __restrict__ wt,
                       u16* __restrict__ Mt, float* __restrict__ c0g)
{
  __shared__ float kvs[1024];
  const int b = blockIdx.x, t = threadIdx.x;
  const float inv_len = 1.0f / (float)vlen[b];
  #pragma unroll
  for (int k=0; k<4; ++k){
    const int idx = t + 256*k;
    float s = 0.f;
    for (int r=0; r<nrep; ++r) s += kvgr[((size_t)r*16 + b)*1024 + idx];
    kvs[idx] = s * inv_len;
  }
  __syncthreads();
  for (int k=0; k<32; ++k){
    const int o = t + 256*k;           // o < 8192
    const int e = o >> 7, j = o & 127;
    const int h = e >> 3, e8 = e & 7;
    const int ks4 = j >> 5, gg = (j >> 3) & 3, el = j & 7;
    float s = 0.f;
    #pragma unroll
    for (int d=0; d<16; ++d){
      const int od = h*16 + d;         // Wq2 chunk 32 + (od>>4)*4 + ks4
      const u16 wv = wt[16384 + (((od>>4)*4 + ks4)*64 + gg*16 + (od&15))*8 + el];
      s += b2f(wv) * kvs[h*128 + d*8 + e8];
    }
    const int n3 = e >> 4, cc = e & 15;
    Mt[(size_t)b*8192 + ((n3*4 + ks4)*64 + gg*16 + cc)*8 + el] = bfc(s);
  }
  if (t < 64){
    const int e = t, h = e >> 3, e8 = e & 7;
    float s = 0.f;
    #pragma unroll
    for (int d=0; d<16; ++d)
      s += bq2[h*16+d] * INVS * kvs[h*128 + d*8 + e8];
    c0g[b*64 + e] = s;
  }
}

// ---- stage 2: persistent 4-wave blocks; Wq1 (32KB) in LDS ----
__global__ __launch_bounds__(256, 2) void dk_stage2(
    const float* __restrict__ qsp, const float* __restrict__ qssp,
    const float* __restrict__ bq1,
    const float* __restrict__ lnw_g, const float* __restrict__ lnb_g,
    const u16* __restrict__ wt, const u16* __restrict__ Mt,
    const float* __restrict__ c0g, float* __restrict__ outp)
{
  __shared__ u16 sH1[4][32*LDH];       // per-wave H1 (8704B); f32[32][68] later
  __shared__ u16 sW[16384];            // 32KB Wq1, chunk ch at sW+ch*512
  const int tid = threadIdx.x;
  const int w = tid >> 6, l = tid & 63;
  const int c = l & 15, g = l >> 4;
  u16* H1 = sH1[w];
  const f32x4 z4 = {0.f,0.f,0.f,0.f};

  // stage Wq1 chunks 0-31 (8 DMA per wave)
  #pragma unroll
  for (int j=0; j<8; ++j){
    const int ch = w*8 + j;
    gld_lds16(wt + ((size_t)ch*64 + l)*8, &sW[(size_t)ch*512]);
  }
  __syncthreads();

  for (int u = blockIdx.x*4 + w; u < 4096; u += gridDim.x*4){
    const int b  = u >> 8;
    const int ju = u & 255;
    const int rbase = ju*32;
    const size_t row0 = (size_t)b*8192 + rbase;
    const u16* Mb = Mt + (size_t)b*8192;

    // ---- pinned group 1: 16 xq loads (dies into GEMM1q before bm loads) ----
    f32x4 xqf[16];
    #pragma unroll
    for (int ks4=0; ks4<4; ++ks4){
      #pragma unroll
      for (int nt=0; nt<2; ++nt){
        const int kk = ks4*32 + 8*g;
        const float* src = (ks4 < 2) ? (qssp + (row0 + nt*16 + c)*64 + kk)
                                     : (qsp  + (row0 + nt*16 + c)*64 + (kk - 64));
        xqf[(ks4*2+nt)*2+0] = *(const f32x4*)src;
        xqf[(ks4*2+nt)*2+1] = *(const f32x4*)(src+4);
      }
    }
    SBAR();

    // ---- T-GEMM1q (sW reads unfenced; compiler pipelines ds_read) ----
    {
      short8 xq[4][2];
      #pragma unroll
      for (int ks4=0; ks4<4; ++ks4)
        #pragma unroll
        for (int nt=0; nt<2; ++nt)
          xq[ks4][nt] = cvt8(xqf[(ks4*2+nt)*2+0], xqf[(ks4*2+nt)*2+1]);
      f32x4 acc[8][2];
      #pragma unroll
      for (int mt=0; mt<8; ++mt){ acc[mt][0]=z4; acc[mt][1]=z4; }
      #pragma unroll
      for (int ks4=0; ks4<4; ++ks4){
        short8 wa[8];
        #pragma unroll
        for (int mt=0; mt<8; ++mt)
          wa[mt] = *(const short8*)&sW[(size_t)(mt*4+ks4)*512 + l*8];
        #pragma unroll
        for (int mt=0; mt<8; ++mt){
          acc[mt][0] = MFMA(wa[mt], xq[ks4][0], acc[mt][0]);
          acc[mt][1] = MFMA(wa[mt], xq[ks4][1], acc[mt][1]);
        }
      }
      #pragma unroll
      for (int mt=0; mt<8; ++mt){
        const f32x4 bia = *(const f32x4*)&bq1[mt*16 + 4*g];
        #pragma unroll
        for (int nt=0; nt<2; ++nt){
          uint2 pp;
          pp.x = pack2(gelu_f(acc[mt][nt][0]+bia[0]), gelu_f(acc[mt][nt][1]+bia[1]));
          pp.y = pack2(gelu_f(acc[mt][nt][2]+bia[2]), gelu_f(acc[mt][nt][3]+bia[3]));
          *(uint2*)&H1[(nt*16 + c)*LDH + mt*16 + 4*g] = pp;
        }
      }
    }
    // ---- pinned group 2: 16 M-fragment loads; then GEMMM ----
    f32x4 acc3[2][4];
    #pragma unroll
    for (int n3=0; n3<4; ++n3){ acc3[0][n3]=z4; acc3[1][n3]=z4; }
    {
      short8 bm[16];
      #pragma unroll
      for (int ks4=0; ks4<4; ++ks4)
        #pragma unroll
        for (int n3=0; n3<4; ++n3)
          bm[ks4*4+n3] = *(const short8*)&Mb[((n3*4+ks4)*64 + l)*8];
      SBAR();
      #pragma unroll
      for (int ks4=0; ks4<4; ++ks4){
        const short8 aq0 = *(const short8*)&H1[(c     )*LDH + ks4*32 + 8*g];
        const short8 aq1 = *(const short8*)&H1[(16 + c)*LDH + ks4*32 + 8*g];
        #pragma unroll
        for (int n3=0; n3<4; ++n3){
          acc3[0][n3] = MFMA(aq0, bm[ks4*4+n3], acc3[0][n3]);
          acc3[1][n3] = MFMA(aq1, bm[ks4*4+n3], acc3[1][n3]);
        }
      }
    }
    float c0v[4];
    #pragma unroll
    for (int n3=0; n3<4; ++n3) c0v[n3] = c0g[b*64 + n3*16 + c];
    // ---- LayerNorm over 64 -> LDS transpose (f32 [32][68]) ----
    float lnw[4], lnb[4];
    #pragma unroll
    for (int n3=0; n3<4; ++n3){ lnw[n3] = lnw_g[n3*16 + c]; lnb[n3] = lnb_g[n3*16 + c]; }
    float* Tb = (float*)H1;            // H1 dead after GEMMM reads
    #pragma unroll
    for (int mt=0; mt<2; ++mt){
      #pragma unroll
      for (int r=0; r<4; ++r){
        float s1 = 0.f, s2 = 0.f;
        #pragma unroll
        for (int n3=0; n3<4; ++n3){
          float v = acc3[mt][n3][r] + c0v[n3];
          s1 += v; s2 += v*v;
        }
        #pragma unroll
        for (int m=1; m<16; m<<=1){
          s1 += __shfl_xor(s1, m, 64);
          s2 += __shfl_xor(s2, m, 64);
        }
        const float mu = s1 * (1.0f/64.0f);
        const float var = s2 * (1.0f/64.0f) - mu*mu;
        const float rs = rsqrtf(var + 1e-6f);
        const int rloc = mt*16 + 4*g + r;
        #pragma unroll
        for (int n3=0; n3<4; ++n3)
          Tb[rloc*68 + n3*16 + c] = (acc3[mt][n3][r] + c0v[n3] - mu)*rs*lnw[n3] + lnb[n3];
      }
    }
    // ---- coalesced store: 8 x f32x4 ----
    float* ob = outp + row0*64;
    #pragma unroll
    for (int i=0; i<8; ++i){
      const int row = i*4 + (l>>4);
      const f32x4 vv = *(const f32x4*)&Tb[row*68 + (l&15)*4];
      *(f32x4*)(ob + row*64 + (l&15)*4) = vv;
    }
  }
}

extern "C" void kernel_launch(void* const* d_in, const int* in_sizes, int n_in,
                              void* d_out, int out_size, void* d_ws, size_t ws_size,
                              hipStream_t stream)
{
  const float* qs   = (const float*)d_in[0];
  const float* ks   = (const float*)d_in[1];
  const float* vs   = (const float*)d_in[2];
  const float* qs_s = (const float*)d_in[3];
  const float* ks_s = (const float*)d_in[4];
  const int*   vl   = (const int*)d_in[5];
  const float* Wq1  = (const float*)d_in[6];
  const float* bq1  = (const float*)d_in[7];
  const float* Wq2  = (const float*)d_in[8];
  const float* bq2  = (const float*)d_in[9];
  const float* Wv1  = (const float*)d_in[10];
  const float* bv1  = (const float*)d_in[11];
  const float* Wv2  = (const float*)d_in[12];
  const float* bv2  = (const float*)d_in[13];
  const float* lnw  = (const float*)d_in[14];
  const float* lnb  = (const float*)d_in[15];
  (void)in_sizes; (void)n_in; (void)out_size;

  // ws layout: kvgr (nrep*64KB) | wt 96KB | Mt 256KB | c0 4KB
  const size_t fixed = 96*1024 + 256*1024 + 4096;
  int nrep = 4;
  while (nrep > 1 && (size_t)nrep*65536 + fixed > ws_size) nrep >>= 1;
  float* kvgr = (float*)d_ws;
  u16*   wt   = (u16*)((char*)d_ws + (size_t)nrep*65536);
  u16*   Mt   = (u16*)((char*)wt + 96*1024);
  float* c0   = (float*)((char*)Mt + 256*1024);

  hipMemsetAsync(kvgr, 0, (size_t)nrep*65536, stream);
  dk_prep<<<192, 256, 0, stream>>>(Wq1, Wq2, Wv1, Wv2, wt);
  dk_stage1<<<256, 256, 0, stream>>>(ks, ks_s, vs, vl, bq1, bq2, bv1, bv2,
                                     wt, kvgr, nrep - 1);
  dk_mid<<<16, 256, 0, stream>>>(kvgr, nrep, vl, bq2, wt, Mt, c0);
  dk_stage2<<<512, 256, 0, stream>>>(qs, qs_s, bq1, lnw, lnb, wt, Mt, c0,
                                     (float*)d_out);
}